// Round 3
// baseline (968.591 us; speedup 1.0000x reference)
//
#include <hip/hip_runtime.h>

// Viterbi / CRF decode: B=32, S=512, T=128. One workgroup per batch.
// R3: LDS-pipe diet. R2 post-mortem: per-CU LDS pipe was the bottleneck
// (~128 ds_bpermute + 64 serial-reduce reads + partial writes ~ 1500 cyc/step).
// New structure per step:
//   - each thread computes a 4i x 4j tile argmax (exact ref fp order),
//   - writes 4 packed u64 {val_bits, i} partials with 2 contiguous ds_write_b128,
//   - 2 waves reduce 32 candidates per column via b64 reads, 4 parallel 8-chains
//     + strict-> merges (contiguous gg blocks => strict-> preserves first-max),
//   - barriers are lgkmcnt-only (no vmcnt drain; global prefetch stays in flight),
//   - 2-deep prefetch pipeline with strength-reduced pointers (+= T*T).
// Tie-break invariant: candidates always combined in ascending-i order with
// strict >, or merged across ascending blocks with strict > (min-i on ties).

constexpr int S = 512;
constexpr int T = 128;

__device__ __forceinline__ void bar_lds() {
    // LDS-only fence + barrier: does NOT drain vmcnt.
    asm volatile("s_waitcnt lgkmcnt(0)" ::: "memory");
    __builtin_amdgcn_s_barrier();
}

__device__ __forceinline__ unsigned long long pack_vi(float v, int i) {
    return ((unsigned long long)__float_as_uint(v) << 32) | (unsigned int)i;
}

__global__ __launch_bounds__(1024, 1)
void viterbi_fused(const float* __restrict__ c0, const float* __restrict__ c1,
                   const int* __restrict__ sofp, const int* __restrict__ eofp,
                   int* __restrict__ out)
{
    __shared__ float fs[2][T];                   // ping-pong forward scores
    __shared__ unsigned long long part[32][T];   // 32 KB packed {val, i} partials
    __shared__ unsigned char bp[S][T];           // 64 KB backpointers

    const int b   = blockIdx.x;
    const int tid = (int)threadIdx.x;
    const int jq  = tid & 31;                    // j-quad: j = 4*jq .. +3
    const int g   = tid >> 5;                    // i-group 0..31: i = 4*g .. +3
    const int col = jq * 4;
    const int row = g * 4;

    const float* c0b = c0 + (size_t)b * (S + 1) * T * T;
    const float* c1b = c1 + (size_t)b * (S + 1) * T;

    // fs[0][j] = c0[b,0,sof,j] * c1[b,0,j]  (multiply at step 0, per reference)
    if (tid < T) {
        const int sof = sofp[0];
        fs[0][tid] = c0b[(size_t)sof * T + tid] * c1b[tid];
    }

    // Two-deep pipeline pointers (per-lane); rows via immediate offsets.
    const float* pA = c0b + (size_t)T * T + (size_t)row * T + col;   // step 1
    const float* qA = c1b + T + col;
    const float* pB = pA + T * T;                                     // step 2
    const float* qB = qA + T;

    float4 A0 = *(const float4*)(pA);
    float4 A1 = *(const float4*)(pA + T);
    float4 A2 = *(const float4*)(pA + 2 * T);
    float4 A3 = *(const float4*)(pA + 3 * T);
    float4 At = *(const float4*)(qA);
    float4 B0 = *(const float4*)(pB);
    float4 B1 = *(const float4*)(pB + T);
    float4 B2 = *(const float4*)(pB + 2 * T);
    float4 B3 = *(const float4*)(pB + 3 * T);
    float4 Bt = *(const float4*)(qB);

    bar_lds();  // fs[0] visible

    int p = 0;

    auto STEP = [&](int s, float4& a0, float4& a1, float4& a2, float4& a3,
                    float4& tv, const float*& pp, const float*& qq) {
        const float f0 = fs[p][row + 0];
        const float f1 = fs[p][row + 1];
        const float f2 = fs[p][row + 2];
        const float f3 = fs[p][row + 3];

        // 4x4 tile, exact ref order (fs[i]+t1[j])+t0[i,j]; strict > = first max.
        float bx, by, bz, bw; int ix, iy, iz, iw; float v;
        bx = (f0 + tv.x) + a0.x; ix = row;
        by = (f0 + tv.y) + a0.y; iy = row;
        bz = (f0 + tv.z) + a0.z; iz = row;
        bw = (f0 + tv.w) + a0.w; iw = row;

        v = (f1 + tv.x) + a1.x; if (v > bx) { bx = v; ix = row + 1; }
        v = (f1 + tv.y) + a1.y; if (v > by) { by = v; iy = row + 1; }
        v = (f1 + tv.z) + a1.z; if (v > bz) { bz = v; iz = row + 1; }
        v = (f1 + tv.w) + a1.w; if (v > bw) { bw = v; iw = row + 1; }

        v = (f2 + tv.x) + a2.x; if (v > bx) { bx = v; ix = row + 2; }
        v = (f2 + tv.y) + a2.y; if (v > by) { by = v; iy = row + 2; }
        v = (f2 + tv.z) + a2.z; if (v > bz) { bz = v; iz = row + 2; }
        v = (f2 + tv.w) + a2.w; if (v > bw) { bw = v; iw = row + 2; }

        v = (f3 + tv.x) + a3.x; if (v > bx) { bx = v; ix = row + 3; }
        v = (f3 + tv.y) + a3.y; if (v > by) { by = v; iy = row + 3; }
        v = (f3 + tv.z) + a3.z; if (v > bz) { bz = v; iz = row + 3; }
        v = (f3 + tv.w) + a3.w; if (v > bw) { bw = v; iw = row + 3; }

        // Prefetch step s+2 into this now-dead register set (stays in flight
        // across the lgkmcnt-only barriers below).
        if (s + 2 <= S) {
            pp += 2 * T * T;
            qq += 2 * T;
            a0 = *(const float4*)(pp);
            a1 = *(const float4*)(pp + T);
            a2 = *(const float4*)(pp + 2 * T);
            a3 = *(const float4*)(pp + 3 * T);
            tv = *(const float4*)(qq);
        }

        // Packed partial write: 32 contiguous bytes per lane (2 x ds_write_b128).
        ulonglong2 w0, w1;
        w0.x = pack_vi(bx, ix);
        w0.y = pack_vi(by, iy);
        w1.x = pack_vi(bz, iz);
        w1.y = pack_vi(bw, iw);
        *(ulonglong2*)&part[g][col]     = w0;
        *(ulonglong2*)&part[g][col + 2] = w1;
        bar_lds();

        // Final reduce: 128 threads, column j = tid. 32 candidates as 4
        // independent 8-chains (ascending gg), then strict-> merges.
        if (tid < T) {
            float v0, v1c, v2c, v3c; int i0, i1c, i2c, i3c;
            {
                unsigned long long k = part[0][tid];
                v0 = __uint_as_float((unsigned)(k >> 32)); i0 = (int)(unsigned)k;
                #pragma unroll
                for (int gg = 1; gg < 8; ++gg) {
                    unsigned long long c = part[gg][tid];
                    float vv = __uint_as_float((unsigned)(c >> 32));
                    if (vv > v0) { v0 = vv; i0 = (int)(unsigned)c; }
                }
            }
            {
                unsigned long long k = part[8][tid];
                v1c = __uint_as_float((unsigned)(k >> 32)); i1c = (int)(unsigned)k;
                #pragma unroll
                for (int gg = 9; gg < 16; ++gg) {
                    unsigned long long c = part[gg][tid];
                    float vv = __uint_as_float((unsigned)(c >> 32));
                    if (vv > v1c) { v1c = vv; i1c = (int)(unsigned)c; }
                }
            }
            {
                unsigned long long k = part[16][tid];
                v2c = __uint_as_float((unsigned)(k >> 32)); i2c = (int)(unsigned)k;
                #pragma unroll
                for (int gg = 17; gg < 24; ++gg) {
                    unsigned long long c = part[gg][tid];
                    float vv = __uint_as_float((unsigned)(c >> 32));
                    if (vv > v2c) { v2c = vv; i2c = (int)(unsigned)c; }
                }
            }
            {
                unsigned long long k = part[24][tid];
                v3c = __uint_as_float((unsigned)(k >> 32)); i3c = (int)(unsigned)k;
                #pragma unroll
                for (int gg = 25; gg < 32; ++gg) {
                    unsigned long long c = part[gg][tid];
                    float vv = __uint_as_float((unsigned)(c >> 32));
                    if (vv > v3c) { v3c = vv; i3c = (int)(unsigned)c; }
                }
            }
            // Merge ascending blocks; strict > keeps the lowest-i winner.
            if (v1c > v0) { v0 = v1c; i0 = i1c; }
            if (v2c > v0) { v0 = v2c; i0 = i2c; }
            if (v3c > v0) { v0 = v3c; i0 = i3c; }

            fs[p ^ 1][tid] = v0;
            bp[s - 1][tid] = (unsigned char)i0;
        }
        bar_lds();
        p ^= 1;
    };

    for (int s = 1; s <= S; s += 2) {
        STEP(s,     A0, A1, A2, A3, At, pA, qA);
        STEP(s + 1, B0, B1, B2, B3, Bt, pB, qB);
    }

    // Backtrack (serial pointer chase in LDS).
    if (tid == 0) {
        const int eof = eofp[0];
        int ptr = bp[S - 1][eof];
        for (int idx = S - 1; idx >= 0; --idx) {
            ptr = bp[idx][ptr];
            out[(size_t)b * S + idx] = ptr;
        }
    }
}

extern "C" void kernel_launch(void* const* d_in, const int* in_sizes, int n_in,
                              void* d_out, int out_size, void* d_ws, size_t ws_size,
                              hipStream_t stream)
{
    const float* c0  = (const float*)d_in[0];
    const float* c1  = (const float*)d_in[1];
    const int*   sof = (const int*)d_in[2];
    const int*   eof = (const int*)d_in[3];
    int*         out = (int*)d_out;

    const int B = in_sizes[1] / ((S + 1) * T);   // 32
    viterbi_fused<<<dim3(B), dim3(1024), 0, stream>>>(c0, c1, sof, eof, out);
}

// Round 4
// 697.787 us; speedup vs baseline: 1.3881x; 1.3881x over previous
//
#include <hip/hip_runtime.h>

// Viterbi / CRF decode: B=32, S=512, T=128.
// R4: 8 blocks per batch (i-sliced) -> 256 CUs active instead of 32.
// Cross-block per-step exchange via L2 scratch with self-validating tagged
// u64 atomics (agent scope, relaxed): payload = {f32 val (hi32) | s<<8 | i}.
// Deadlock-free: block publishes step s+1 only after consuming step s, so the
// parity slot (s&1) is never overwritten before all consumers of s finished.
// Stale-tag hits across graph replays return bitwise-identical values
// (deterministic recurrence on unchanged inputs) -> still correct.
// Tie-break (first-max, lowest i) preserved everywhere: ascending-i combine
// with strict >, ascending-slice merge with strict >.
// Backtrack = 2nd kernel (kernel boundary flushes bp writes): bp batch slice
// (64 KB) -> LDS, serial pointer chase.

constexpr int S    = 512;
constexpr int T    = 128;
constexpr int NSL  = 8;          // i-slices (blocks) per batch
constexpr int ROWS = T / NSL;    // 16 rows per slice

__device__ __forceinline__ void bar_lds() {
    // LDS-only fence + barrier: does NOT drain vmcnt (global prefetch stays
    // in flight across barriers).
    asm volatile("s_waitcnt lgkmcnt(0)" ::: "memory");
    __builtin_amdgcn_s_barrier();
}

__device__ __forceinline__ unsigned long long pack_vi(float v, int i) {
    return ((unsigned long long)__float_as_uint(v) << 32) | (unsigned int)i;
}
__device__ __forceinline__ float hi_f(unsigned long long m) {
    return __uint_as_float((unsigned)(m >> 32));
}

// ---------------- forward: grid = 32 batches x 8 slices, 256 thr ----------
__global__ __launch_bounds__(256, 1)
void viterbi_fwd(const float* __restrict__ c0, const float* __restrict__ c1,
                 const int* __restrict__ sofp,
                 unsigned long long* __restrict__ pub,  // [32][2][8][128] u64
                 unsigned char* __restrict__ bp)        // [32][512][128] u8
{
    __shared__ float fsl[ROWS];                 // block's 16 forward scores
    __shared__ unsigned long long part[8][T];   // intra-block partials (8 KB)

    const int g    = blockIdx.x;
    const int b    = g & 31;       // batch
    const int k    = g >> 5;       // slice; g%8 == b%8 -> slices share an XCD
    const int tid  = (int)threadIdx.x;
    const int r    = tid >> 5;     // 0..7  (i-pair group)
    const int c    = tid & 31;     // j-quad
    const int j0   = c * 4;
    const int row0 = k * ROWS;     // global i base of this slice
    const int iA   = row0 + 2 * r; // this thread's two (adjacent!) i rows
    const int iB   = iA + 1;

    const float* c0b = c0 + (size_t)b * (S + 1) * T * T;
    const float* c1b = c1 + (size_t)b * (S + 1) * T;
    unsigned long long* pubB = pub + (size_t)b * 2 * NSL * T;

    // fs0[j] = c0[b,0,sof,j] * c1[b,0,j]  (multiply at step 0, per reference);
    // block only needs its own 16 entries.
    if (tid < ROWS) {
        const int sof = sofp[0];
        fsl[tid] = c0b[(size_t)sof * T + row0 + tid] * c1b[row0 + tid];
    }

    // Streaming per-thread pointers; 2-deep pipeline (reg sets A/B).
    const float* pA = c0b + (size_t)T * T + (size_t)iA * T + j0;  // step 1
    const float* qA = c1b + T + j0;
    const float* pB = pA + T * T;                                  // step 2
    const float* qB = qA + T;

    float4 A0 = *(const float4*)(pA);
    float4 A1 = *(const float4*)(pA + T);
    float4 At = *(const float4*)(qA);
    float4 B0 = *(const float4*)(pB);
    float4 B1 = *(const float4*)(pB + T);
    float4 Bt = *(const float4*)(qB);

    bar_lds();  // fsl visible

    auto STEP = [&](int s, float4& a0, float4& a1, float4& tv,
                    const float*& pp, const float*& qq) {
        const float f0 = fsl[2 * r];
        const float f1 = fsl[2 * r + 1];

        // 2i x 4j tile, exact ref fp order (fs[i]+t1[j])+t0[i,j];
        // ascending i (iA then iB) with strict > keeps lowest-i on ties.
        float bx, by, bz, bw; int ix, iy, iz, iw; float v;
        bx = (f0 + tv.x) + a0.x; ix = iA;
        by = (f0 + tv.y) + a0.y; iy = iA;
        bz = (f0 + tv.z) + a0.z; iz = iA;
        bw = (f0 + tv.w) + a0.w; iw = iA;
        v = (f1 + tv.x) + a1.x; if (v > bx) { bx = v; ix = iB; }
        v = (f1 + tv.y) + a1.y; if (v > by) { by = v; iy = iB; }
        v = (f1 + tv.z) + a1.z; if (v > bz) { bz = v; iz = iB; }
        v = (f1 + tv.w) + a1.w; if (v > bw) { bw = v; iw = iB; }

        // Prefetch step s+2 into this now-dead register set (no vmcnt drain
        // at our barriers -> stays in flight ~1.5 iterations).
        if (s + 2 <= S) {
            pp += 2 * T * T;
            qq += 2 * T;
            a0 = *(const float4*)(pp);
            a1 = *(const float4*)(pp + T);
            tv = *(const float4*)(qq);
        }

        // Intra-block partials: part[r][j], i-pair {2r,2r+1} ascending in r.
        ulonglong2 w0, w1;
        w0.x = pack_vi(bx, ix); w0.y = pack_vi(by, iy);
        w1.x = pack_vi(bz, iz); w1.y = pack_vi(bw, iw);
        *(ulonglong2*)&part[r][j0]     = w0;
        *(ulonglong2*)&part[r][j0 + 2] = w1;
        bar_lds();

        // Merge 8 i-pair groups (ascending r => ascending i blocks) and
        // publish this slice's partial for every j.
        if (tid < T) {
            unsigned long long m = part[0][tid];
            float mv = hi_f(m);
            #pragma unroll
            for (int rr = 1; rr < 8; ++rr) {
                unsigned long long cnd = part[rr][tid];
                float cv = hi_f(cnd);
                if (cv > mv) { mv = cv; m = cnd; }
            }
            unsigned long long payload =
                (m & 0xffffffff00000000ull) |
                (unsigned)(((unsigned)s << 8) | (unsigned)(m & 0xffu));
            __hip_atomic_store(&pubB[(size_t)((s & 1) * NSL + k) * T + tid],
                               payload, __ATOMIC_RELAXED,
                               __HIP_MEMORY_SCOPE_AGENT);
        }

        // Gather the 8 slice-partials for this block's own 16 columns,
        // spin on self-validating tags, merge (ascending slice = ascending i).
        if (tid < ROWS) {
            const unsigned long long* ps =
                pubB + (size_t)(s & 1) * NSL * T + (row0 + tid);
            unsigned long long cand[8];
            for (;;) {
                bool ok = true;
                #pragma unroll
                for (int sl = 0; sl < 8; ++sl)
                    cand[sl] = __hip_atomic_load(ps + sl * T, __ATOMIC_RELAXED,
                                                 __HIP_MEMORY_SCOPE_AGENT);
                #pragma unroll
                for (int sl = 0; sl < 8; ++sl)
                    ok &= (((unsigned)cand[sl] >> 8) == (unsigned)s);
                if (ok) break;
            }
            unsigned long long m = cand[0];
            float mv = hi_f(m);
            #pragma unroll
            for (int sl = 1; sl < 8; ++sl) {
                float cv = hi_f(cand[sl]);
                if (cv > mv) { mv = cv; m = cand[sl]; }
            }
            fsl[tid] = mv;
            bp[((size_t)b * S + (s - 1)) * T + row0 + tid] =
                (unsigned char)(m & 0xffu);
        }
        bar_lds();
    };

    for (int s = 1; s <= S; s += 2) {
        STEP(s,     A0, A1, At, pA, qA);
        STEP(s + 1, B0, B1, Bt, pB, qB);
    }
}

// ---------------- backtrack: one block per batch ---------------------------
__global__ __launch_bounds__(1024, 1)
void viterbi_bwd(const unsigned char* __restrict__ bp,
                 const int* __restrict__ eofp, int* __restrict__ out)
{
    __shared__ unsigned char lbp[S][T];  // 64 KB
    const int b   = blockIdx.x;
    const int tid = (int)threadIdx.x;

    const uint4* s4 = (const uint4*)(bp + (size_t)b * S * T);
    uint4* d4 = (uint4*)&lbp[0][0];
    #pragma unroll
    for (int it = 0; it < 4; ++it) d4[tid + it * 1024] = s4[tid + it * 1024];
    __syncthreads();

    if (tid == 0) {
        int ptr = lbp[S - 1][eofp[0]];
        for (int idx = S - 1; idx >= 0; --idx) {
            ptr = lbp[idx][ptr];
            out[(size_t)b * S + idx] = ptr;
        }
    }
}

// ---------------- fallback (proven R2 kernel) if ws too small --------------
__global__ __launch_bounds__(1024, 1)
void viterbi_fused_fb(const float* __restrict__ c0, const float* __restrict__ c1,
                      const int* __restrict__ sofp, const int* __restrict__ eofp,
                      int* __restrict__ out)
{
    __shared__ float fs[2][T];
    __shared__ float pmax[32][T];
    __shared__ int   parg[32][T];
    __shared__ unsigned char bpl[S][T];

    const int b   = blockIdx.x;
    const int tid = (int)threadIdx.x;
    const int jq  = tid & 31;
    const int g   = tid >> 5;
    const int col = jq * 4;
    const int row = g * 4;

    const float* c0b = c0 + (size_t)b * (S + 1) * T * T;
    const float* c1b = c1 + (size_t)b * (S + 1) * T;

    if (tid < T) {
        const int sof = sofp[0];
        fs[0][tid] = c0b[(size_t)sof * T + tid] * c1b[tid];
    }
    __syncthreads();

    const float* t0p = c0b + (size_t)T * T;
    float4 a0 = *(const float4*)(t0p + (size_t)(row + 0) * T + col);
    float4 a1 = *(const float4*)(t0p + (size_t)(row + 1) * T + col);
    float4 a2 = *(const float4*)(t0p + (size_t)(row + 2) * T + col);
    float4 a3 = *(const float4*)(t0p + (size_t)(row + 3) * T + col);
    float4 tv = *(const float4*)(c1b + T + col);

    int p = 0;
    for (int s = 1; s <= S; ++s) {
        float4 b0 = make_float4(0.f,0.f,0.f,0.f), b1 = b0, b2 = b0, b3 = b0, bt = b0;
        if (s < S) {
            const float* n0 = c0b + (size_t)(s + 1) * T * T;
            b0 = *(const float4*)(n0 + (size_t)(row + 0) * T + col);
            b1 = *(const float4*)(n0 + (size_t)(row + 1) * T + col);
            b2 = *(const float4*)(n0 + (size_t)(row + 2) * T + col);
            b3 = *(const float4*)(n0 + (size_t)(row + 3) * T + col);
            bt = *(const float4*)(c1b + (size_t)(s + 1) * T + col);
        }
        const float f0 = fs[p][row + 0];
        const float f1 = fs[p][row + 1];
        const float f2 = fs[p][row + 2];
        const float f3 = fs[p][row + 3];

        float bx, by, bz, bw; int ix, iy, iz, iw; float v;
        bx = (f0 + tv.x) + a0.x; ix = row;
        by = (f0 + tv.y) + a0.y; iy = row;
        bz = (f0 + tv.z) + a0.z; iz = row;
        bw = (f0 + tv.w) + a0.w; iw = row;
        v = (f1 + tv.x) + a1.x; if (v > bx) { bx = v; ix = row + 1; }
        v = (f1 + tv.y) + a1.y; if (v > by) { by = v; iy = row + 1; }
        v = (f1 + tv.z) + a1.z; if (v > bz) { bz = v; iz = row + 1; }
        v = (f1 + tv.w) + a1.w; if (v > bw) { bw = v; iw = row + 1; }
        v = (f2 + tv.x) + a2.x; if (v > bx) { bx = v; ix = row + 2; }
        v = (f2 + tv.y) + a2.y; if (v > by) { by = v; iy = row + 2; }
        v = (f2 + tv.z) + a2.z; if (v > bz) { bz = v; iz = row + 2; }
        v = (f2 + tv.w) + a2.w; if (v > bw) { bw = v; iw = row + 2; }
        v = (f3 + tv.x) + a3.x; if (v > bx) { bx = v; ix = row + 3; }
        v = (f3 + tv.y) + a3.y; if (v > by) { by = v; iy = row + 3; }
        v = (f3 + tv.z) + a3.z; if (v > bz) { bz = v; iz = row + 3; }
        v = (f3 + tv.w) + a3.w; if (v > bw) { bw = v; iw = row + 3; }

        *(float4*)&pmax[g][col] = make_float4(bx, by, bz, bw);
        *(int4*)  &parg[g][col] = make_int4(ix, iy, iz, iw);
        __syncthreads();

        if (tid < T) {
            float bb = pmax[0][tid];
            int   ii = parg[0][tid];
            #pragma unroll
            for (int gg = 1; gg < 32; ++gg) {
                float vv = pmax[gg][tid];
                if (vv > bb) { bb = vv; ii = parg[gg][tid]; }
            }
            fs[p ^ 1][tid] = bb;
            bpl[s - 1][tid] = (unsigned char)ii;
        }
        __syncthreads();
        p ^= 1;
        a0 = b0; a1 = b1; a2 = b2; a3 = b3; tv = bt;
    }

    if (tid == 0) {
        const int eof = eofp[0];
        int ptr = bpl[S - 1][eof];
        for (int idx = S - 1; idx >= 0; --idx) {
            ptr = bpl[idx][ptr];
            out[(size_t)b * S + idx] = ptr;
        }
    }
}

extern "C" void kernel_launch(void* const* d_in, const int* in_sizes, int n_in,
                              void* d_out, int out_size, void* d_ws, size_t ws_size,
                              hipStream_t stream)
{
    const float* c0  = (const float*)d_in[0];
    const float* c1  = (const float*)d_in[1];
    const int*   sof = (const int*)d_in[2];
    const int*   eof = (const int*)d_in[3];
    int*         out = (int*)d_out;

    const int B = in_sizes[1] / ((S + 1) * T);   // 32

    const size_t pub_bytes = (size_t)B * 2 * NSL * T * 8;   // 512 KB
    const size_t bp_bytes  = (size_t)B * S * T;             // 2 MB
    if (ws_size >= pub_bytes + bp_bytes) {
        unsigned long long* pub = (unsigned long long*)d_ws;
        unsigned char* bp = (unsigned char*)d_ws + pub_bytes;
        viterbi_fwd<<<dim3(B * NSL), dim3(256), 0, stream>>>(c0, c1, sof, pub, bp);
        viterbi_bwd<<<dim3(B), dim3(1024), 0, stream>>>(bp, eof, out);
    } else {
        viterbi_fused_fb<<<dim3(B), dim3(1024), 0, stream>>>(c0, c1, sof, eof, out);
    }
}